// Round 1
// baseline (235.424 us; speedup 1.0000x reference)
//
#include <hip/hip_runtime.h>

// Non-local attention: X [8, 64, 64, 64] fp32.
// Per batch b: Q=K=V = X_b^T  [S=4096, D=64];  out = softmax(Q K^T) V, stored [b][c][s].
// Flash-style: BM=64 Q rows/block, BN=64 K cols/iter, bf16 MFMA 16x16x32.

#define SEQ 4096
#define DIM 64
#define BM  64
#define BN  64
#define LDB 72   // bf16 LDS row stride (elements): 144 B -> 2-way bank aliasing only (free)
#define LDO 68   // fp32 LDS row stride for epilogue transpose (272 B, 16B-aligned rows)

typedef __attribute__((ext_vector_type(8))) short  short8;  // 8 bf16 = 4 VGPRs
typedef __attribute__((ext_vector_type(4))) float  f32x4;

__device__ __forceinline__ unsigned short f2bf(float f) {
    union { float f; unsigned int u; } x; x.f = f;
    unsigned int u = x.u + 0x7FFFu + ((x.u >> 16) & 1u);   // RNE (inputs are normal gaussians; no NaN care)
    return (unsigned short)(u >> 16);
}

__global__ __launch_bounds__(256, 2) void attn_kernel(const float* __restrict__ X,
                                                      float* __restrict__ Out) {
    // LDS plan (27648 B total):
    //   sK: [64][72] bf16, K-tile as [m][c]   (for S=QK^T B-frags: 8 consecutive c per lane)
    //   sV: [64][72] bf16, K-tile as [c][m]   (for PV B-frags: 8 consecutive m per lane)
    //   sP: [64][72] bf16, P as [n][m], per-wave 16-row strips
    //   sO: [64][68] fp32 overlays sK+sV in epilogue (17408 <= 18432)
    __shared__ __align__(16) unsigned char smem[27648];
    unsigned short* sK = (unsigned short*)smem;
    unsigned short* sV = (unsigned short*)(smem + 9216);
    unsigned short* sP = (unsigned short*)(smem + 18432);
    float*          sO = (float*)smem;

    const int tid  = threadIdx.x;
    const int lane = tid & 63;
    const int w    = tid >> 6;     // wave 0..3, owns Q rows [16w, 16w+16)
    const int l15  = lane & 15;
    const int quad = lane >> 4;

    const int b  = blockIdx.y;
    const int s0 = blockIdx.x * BM;
    const float* Xb = X + (size_t)b * DIM * SEQ;

    const int mgrp = tid & 15;   // staging: 4 consecutive fast-axis elems
    const int c0   = tid >> 4;   // staging: channel row

    // ---- stage Q tile into sK as [n][c] bf16, read per-wave Q A-frags ----
    for (int cc = 0; cc < 4; ++cc) {
        int c = c0 + 16 * cc;
        const f32x4 v = *(const f32x4*)(Xb + (size_t)c * SEQ + s0 + 4 * mgrp);
        sK[(4 * mgrp + 0) * LDB + c] = f2bf(v.x);
        sK[(4 * mgrp + 1) * LDB + c] = f2bf(v.y);
        sK[(4 * mgrp + 2) * LDB + c] = f2bf(v.z);
        sK[(4 * mgrp + 3) * LDB + c] = f2bf(v.w);
    }
    __syncthreads();
    short8 qf0, qf1;
    {
        const int row = 16 * w + l15;
        qf0 = *(const short8*)(sK + row * LDB + quad * 8);
        qf1 = *(const short8*)(sK + row * LDB + 32 + quad * 8);
    }
    __syncthreads();

    // ---- online-softmax state: lane holds rows n = quad*4 + r (r=0..3) of its wave strip ----
    f32x4 acc_o[4];
    for (int ct = 0; ct < 4; ++ct) acc_o[ct] = (f32x4){0.f, 0.f, 0.f, 0.f};
    float m_i[4] = {-1e30f, -1e30f, -1e30f, -1e30f};
    float l_i[4] = {0.f, 0.f, 0.f, 0.f};

    for (int kt = 0; kt < SEQ / BN; ++kt) {
        const int m0 = kt * BN;

        // ---- stage K/V tile: global fp32 [c][m] -> sK [m][c], sV [c][m] (bf16) ----
        for (int cc = 0; cc < 4; ++cc) {
            int c = c0 + 16 * cc;
            const f32x4 v = *(const f32x4*)(Xb + (size_t)c * SEQ + m0 + 4 * mgrp);
            unsigned short h0 = f2bf(v.x), h1 = f2bf(v.y), h2 = f2bf(v.z), h3 = f2bf(v.w);
            *(ushort4*)(sV + c * LDB + 4 * mgrp) = make_ushort4(h0, h1, h2, h3);
            sK[(4 * mgrp + 0) * LDB + c] = h0;
            sK[(4 * mgrp + 1) * LDB + c] = h1;
            sK[(4 * mgrp + 2) * LDB + c] = h2;
            sK[(4 * mgrp + 3) * LDB + c] = h3;
        }
        __syncthreads();   // staging visible to all waves

        // ---- V B-frags into regs now (so no barrier needed between PV and next staging) ----
        short8 vf[2][4];
        for (int ks = 0; ks < 2; ++ks)
            for (int ct = 0; ct < 4; ++ct)
                vf[ks][ct] = *(const short8*)(sV + (16 * ct + l15) * LDB + ks * 32 + quad * 8);

        // ---- S = Q K^T for this wave's 16x64 strip ----
        f32x4 acc_s[4];
        for (int mt = 0; mt < 4; ++mt) {
            const int row = 16 * mt + l15;
            const short8 kf0 = *(const short8*)(sK + row * LDB + quad * 8);
            const short8 kf1 = *(const short8*)(sK + row * LDB + 32 + quad * 8);
            f32x4 a = (f32x4){0.f, 0.f, 0.f, 0.f};
            a = __builtin_amdgcn_mfma_f32_16x16x32_bf16(qf0, kf0, a, 0, 0, 0);
            a = __builtin_amdgcn_mfma_f32_16x16x32_bf16(qf1, kf1, a, 0, 0, 0);
            acc_s[mt] = a;
        }

        // ---- online softmax over m (cols): local over 4 m-tiles, then 16-lane quad-group reduce ----
        float alpha[4];
        for (int r = 0; r < 4; ++r) {
            float mx = fmaxf(fmaxf(acc_s[0][r], acc_s[1][r]), fmaxf(acc_s[2][r], acc_s[3][r]));
            mx = fmaxf(mx, __shfl_xor(mx, 1));
            mx = fmaxf(mx, __shfl_xor(mx, 2));
            mx = fmaxf(mx, __shfl_xor(mx, 4));
            mx = fmaxf(mx, __shfl_xor(mx, 8));
            const float mnew = fmaxf(m_i[r], mx);
            alpha[r] = __expf(m_i[r] - mnew);
            m_i[r] = mnew;
        }

        float rowsum[4] = {0.f, 0.f, 0.f, 0.f};
        unsigned short pb[4][4];
        for (int mt = 0; mt < 4; ++mt)
            for (int r = 0; r < 4; ++r) {
                const float p = __expf(acc_s[mt][r] - m_i[r]);
                rowsum[r] += p;
                pb[mt][r] = f2bf(p);
            }
        for (int r = 0; r < 4; ++r) {
            float s = rowsum[r];
            s += __shfl_xor(s, 1);
            s += __shfl_xor(s, 2);
            s += __shfl_xor(s, 4);
            s += __shfl_xor(s, 8);
            l_i[r] = alpha[r] * l_i[r] + s;
        }
        for (int ct = 0; ct < 4; ++ct)
            for (int r = 0; r < 4; ++r)
                acc_o[ct][r] *= alpha[r];

        // ---- P (C-layout) -> LDS [n][m] (per-wave strip) -> A-layout frags ----
        for (int mt = 0; mt < 4; ++mt)
            for (int r = 0; r < 4; ++r)
                sP[(16 * w + quad * 4 + r) * LDB + l15 + 16 * mt] = pb[mt][r];
        __syncthreads();   // also guards sK/sV against next iteration's staging

        const short8 pf0 = *(const short8*)(sP + (16 * w + l15) * LDB + quad * 8);
        const short8 pf1 = *(const short8*)(sP + (16 * w + l15) * LDB + 32 + quad * 8);
        for (int ct = 0; ct < 4; ++ct) {
            acc_o[ct] = __builtin_amdgcn_mfma_f32_16x16x32_bf16(pf0, vf[0][ct], acc_o[ct], 0, 0, 0);
            acc_o[ct] = __builtin_amdgcn_mfma_f32_16x16x32_bf16(pf1, vf[1][ct], acc_o[ct], 0, 0, 0);
        }
    }

    // ---- epilogue: O/l, transpose via LDS (sO overlays sK/sV -- all reads of those done pre-barrier) ----
    float inv[4];
    for (int r = 0; r < 4; ++r) inv[r] = 1.f / l_i[r];
    for (int ct = 0; ct < 4; ++ct) {
        const int c = 16 * ct + l15;
        for (int r = 0; r < 4; ++r)
            sO[c * LDO + 16 * w + quad * 4 + r] = acc_o[ct][r] * inv[r];
    }
    __syncthreads();
    for (int cc = 0; cc < 4; ++cc) {
        const int c = c0 + 16 * cc;
        const f32x4 v = *(const f32x4*)(sO + c * LDO + 4 * mgrp);
        *(f32x4*)(Out + (size_t)b * DIM * SEQ + (size_t)c * SEQ + s0 + 4 * mgrp) = v;
    }
}

extern "C" void kernel_launch(void* const* d_in, const int* in_sizes, int n_in,
                              void* d_out, int out_size, void* d_ws, size_t ws_size,
                              hipStream_t stream) {
    const float* X = (const float*)d_in[0];
    float* Out = (float*)d_out;
    dim3 grid(SEQ / BM, 8);
    attn_kernel<<<grid, 256, 0, stream>>>(X, Out);
}